// Round 5
// baseline (473.747 us; speedup 1.0000x reference)
//
#include <hip/hip_runtime.h>
#include <hip/hip_bf16.h>
#include <hip/hip_fp16.h>
#include <cstdint>
#include <cstddef>

// ---------------------------------------------------------------------------
// FeatureExtractorGAT, round 5.
// Changes vs R4 (438 us; gat1_pass_b stuck at 153 us, 42% HBM / 47% VALU /
// FETCH 410 MB -> latency or L2-miss-path bound):
//  - softmax fused into the gather pass (acc = sum p*g, s = sum p, divide at
//    end) -> gat{1,2}_pass_a kernels and pbuf/inv buffers eliminated.
//  - gat1: 2 waves per node (edge-list split, LDS combine) + U=8 batches.
//  - CSR rows filled in approximate src-sorted order (extra histogram/scan/
//    scatter by src) so concurrent waves sweep the xh1h table in the same
//    window -> L2 temporal locality. Diagnostic: gat1 FETCH_SIZE.
// ---------------------------------------------------------------------------

__global__ void prep_kernel(const float* __restrict__ W1,
                            const float* __restrict__ as1, const float* __restrict__ ad1,
                            const float* __restrict__ W2,
                            const float* __restrict__ as2, const float* __restrict__ ad2,
                            float* __restrict__ wa1, float* __restrict__ wa2)
{
    int t = threadIdx.x;
    if (t < 480) {
        float accs = 0.f, accd = 0.f;
        #pragma unroll 4
        for (int c = 0; c < 96; ++c) {
            float w = W2[t * 96 + c];
            accs += w * as2[c];
            accd += w * ad2[c];
        }
        wa2[t]       = accs;
        wa2[480 + t] = accd;
    }
    if (t < 32) {
        int k = t >> 3, h = t & 7;
        float accs = 0.f, accd = 0.f;
        for (int c = 0; c < 60; ++c) {
            float w = W1[k * 480 + h * 60 + c];
            accs += w * as1[h * 60 + c];
            accd += w * ad1[h * 60 + c];
        }
        wa1[k * 8 + h]      = accs;
        wa1[32 + k * 8 + h] = accd;
    }
}

__global__ void xh1_kernel(const float* __restrict__ x, const float* __restrict__ W1,
                           __half* __restrict__ xh1h, int N)
{
    int idx = blockIdx.x * blockDim.x + threadIdx.x;
    if (idx >= N * 120) return;
    int n = idx / 120;
    int j = (idx - n * 120) * 4;
    float4 xv = *(const float4*)(x + (size_t)n * 4);
    float4 w0 = *(const float4*)(W1 + j);
    float4 w1 = *(const float4*)(W1 + 480 + j);
    float4 w2 = *(const float4*)(W1 + 960 + j);
    float4 w3 = *(const float4*)(W1 + 1440 + j);
    float ox = xv.x * w0.x + xv.y * w1.x + xv.z * w2.x + xv.w * w3.x;
    float oy = xv.x * w0.y + xv.y * w1.y + xv.z * w2.y + xv.w * w3.y;
    float oz = xv.x * w0.z + xv.y * w1.z + xv.z * w2.z + xv.w * w3.z;
    float ow = xv.x * w0.w + xv.y * w1.w + xv.z * w2.w + xv.w * w3.w;
    __half2* dst = (__half2*)(xh1h + (size_t)n * 480 + j);
    dst[0] = __floats2half2_rn(ox, oy);
    dst[1] = __floats2half2_rn(oz, ow);
}

__global__ void a1_kernel(const float* __restrict__ x, const float* __restrict__ wa1,
                          float* __restrict__ a_s1, float* __restrict__ a_d1, int N)
{
    int n = blockIdx.x * blockDim.x + threadIdx.x;
    if (n >= N) return;
    float4 xv = *(const float4*)(x + (size_t)n * 4);
    #pragma unroll
    for (int h = 0; h < 8; ++h) {
        float as = xv.x * wa1[h] + xv.y * wa1[8 + h] + xv.z * wa1[16 + h] + xv.w * wa1[24 + h];
        float ad = xv.x * wa1[32 + h] + xv.y * wa1[40 + h] + xv.z * wa1[48 + h] + xv.w * wa1[56 + h];
        a_s1[n * 8 + h] = as;
        a_d1[n * 8 + h] = ad;
    }
}

// histogram of dst AND src degrees in one pass
__global__ void hist_kernel(const int* __restrict__ ei, int E, int N,
                            int* __restrict__ deg_dst, int* __restrict__ deg_src)
{
    int e = blockIdx.x * blockDim.x + threadIdx.x;
    if (e >= E + N) return;
    int s, d;
    if (e < E) { s = ei[e]; d = ei[E + e]; } else { s = d = e - E; }
    atomicAdd(&deg_dst[d], 1);
    atomicAdd(&deg_src[s], 1);
}

// ---- parallel scan: block-local exclusive scan + block partial
__global__ __launch_bounds__(1024) void scan_blk_kernel(const int* __restrict__ deg, int N,
                                                        int* __restrict__ offs,
                                                        int* __restrict__ partials)
{
    __shared__ int wsum[16];
    int i = blockIdx.x * 1024 + threadIdx.x;
    int lane = threadIdx.x & 63, wid = threadIdx.x >> 6;
    int v = (i < N) ? deg[i] : 0;
    int x = v;
    #pragma unroll
    for (int off = 1; off < 64; off <<= 1) {
        int y = __shfl_up(x, off, 64);
        if (lane >= off) x += y;
    }
    if (lane == 63) wsum[wid] = x;
    __syncthreads();
    if (wid == 0) {
        int wv = (lane < 16) ? wsum[lane] : 0;
        #pragma unroll
        for (int off = 1; off < 16; off <<= 1) {
            int y = __shfl_up(wv, off, 64);
            if (lane >= off) wv += y;
        }
        if (lane < 16) wsum[lane] = wv;
    }
    __syncthreads();
    int excl = (wid ? wsum[wid - 1] : 0) + x - v;
    if (i < N) offs[i] = excl;
    if (threadIdx.x == 1023) partials[blockIdx.x] = wsum[15];
}

// ---- scan of block partials (nb <= 64) + write offs[N] = total
__global__ void scan_part_kernel(int* __restrict__ partials, int nb,
                                 int* __restrict__ offs, int N)
{
    int lane = threadIdx.x & 63;
    int v = (lane < nb) ? partials[lane] : 0;
    int x = v;
    #pragma unroll
    for (int off = 1; off < 64; off <<= 1) {
        int y = __shfl_up(x, off, 64);
        if (lane >= off) x += y;
    }
    if (lane < nb) partials[lane] = x - v;   // exclusive block offsets
    if (lane == 63) offs[N] = x;             // grand total
}

// ---- add block offsets, produce cursor copy
__global__ __launch_bounds__(1024) void scan_add_kernel(int* __restrict__ offs,
                                                        const int* __restrict__ partials,
                                                        int* __restrict__ cursor, int N)
{
    int i = blockIdx.x * 1024 + threadIdx.x;
    if (i < N) {
        int r = offs[i] + partials[blockIdx.x];
        offs[i]   = r;
        cursor[i] = r;
    }
}

// ---- scatter edge ids into src-sorted order
__global__ void esort_kernel(const int* __restrict__ ei, int E, int N,
                             int* __restrict__ scursor, int* __restrict__ esort)
{
    int e = blockIdx.x * blockDim.x + threadIdx.x;
    if (e >= E + N) return;
    int s = (e < E) ? ei[e] : (e - E);
    int pos = atomicAdd(&scursor[s], 1);
    esort[pos] = e;
}

// ---- fill dst-CSR walking edges in (approximate) src-sorted order
__global__ void csrfill_kernel(const int* __restrict__ ei, int E, int N,
                               const int* __restrict__ esort,
                               int* __restrict__ cursor, int* __restrict__ csr)
{
    int i = blockIdx.x * blockDim.x + threadIdx.x;
    if (i >= E + N) return;
    int eid = esort[i];
    int s, d;
    if (eid < E) { s = ei[eid]; d = ei[E + eid]; } else { s = d = eid - E; }
    int pos = atomicAdd(&cursor[d], 1);
    csr[pos] = s;
}

// ---- GAT layer 1, fully fused: p = exp(leaky(a_s+a_d)) inline, unnormalized
// accumulate, divide at end. Block = 128 threads = 2 waves per node; each
// wave takes alternating U=8 edge batches; LDS combine; wave0 does epilogue
// (bias + ELU + store + layer-2 attention dots).
__global__ __launch_bounds__(128) void gat1_fused(
    const int* __restrict__ row_ptr, const int* __restrict__ csr,
    const float* __restrict__ a_s1, const float* __restrict__ a_d1,
    const __half* __restrict__ xh1h, const float* __restrict__ wa2,
    const float* __restrict__ b1,
    float* __restrict__ hout, float* __restrict__ a2s, float* __restrict__ a2d, int N)
{
    int node = blockIdx.x;
    if (node >= N) return;
    int lane = threadIdx.x & 63;
    int wid  = threadIdx.x >> 6;  // 0 or 1
    bool act = lane < 60;
    int col0 = act ? lane * 8 : 0;
    int hA = col0 / 60;
    int hB = (col0 + 7) / 60;
    int sb = 60 * (hA + 1) - col0;  if (sb > 8) sb = 8;  // cols j<sb -> head hA
    float adA = a_d1[(size_t)node * 8 + hA];
    float adB = a_d1[(size_t)node * 8 + hB];

    float acc[8];
    #pragma unroll
    for (int j = 0; j < 8; ++j) acc[j] = 0.f;
    float sA = 0.f, sB = 0.f;

    int beg = row_ptr[node], end = row_ptr[node + 1];
    constexpr int U = 8;
    for (int e0 = beg + wid * U; e0 < end; e0 += 2 * U) {
        int cnt = end - e0;  if (cnt > U) cnt = U;
        int srcs[U];
        #pragma unroll
        for (int u = 0; u < U; ++u) {
            int t = e0 + u;
            srcs[u] = csr[t < end ? t : (end - 1)];
        }
        uint4 raw[U];
        #pragma unroll
        for (int u = 0; u < U; ++u)
            raw[u] = *(const uint4*)(xh1h + (size_t)srcs[u] * 480 + col0);
        float asA[U], asB[U];
        #pragma unroll
        for (int u = 0; u < U; ++u) {
            asA[u] = a_s1[(size_t)srcs[u] * 8 + hA];
            asB[u] = a_s1[(size_t)srcs[u] * 8 + hB];
        }
        #pragma unroll
        for (int u = 0; u < U; ++u) {
            float m = (u < cnt) ? 1.f : 0.f;
            float evA = asA[u] + adA;  evA = evA > 0.f ? evA : 0.2f * evA;
            float evB = asB[u] + adB;  evB = evB > 0.f ? evB : 0.2f * evB;
            float pA = __expf(evA) * m;
            float pB = __expf(evB) * m;
            sA += pA;  sB += pB;
            float2 f0 = __half22float2(*(const __half2*)&raw[u].x);
            float2 f1 = __half22float2(*(const __half2*)&raw[u].y);
            float2 f2 = __half22float2(*(const __half2*)&raw[u].z);
            float2 f3 = __half22float2(*(const __half2*)&raw[u].w);
            float g[8] = {f0.x, f0.y, f1.x, f1.y, f2.x, f2.y, f3.x, f3.y};
            #pragma unroll
            for (int j = 0; j < 8; ++j)
                acc[j] += ((j < sb) ? pA : pB) * g[j];
        }
    }

    __shared__ float lacc[64][9];   // stride 9 -> conflict-free
    __shared__ float lsum[64][2];
    if (wid == 1) {
        #pragma unroll
        for (int j = 0; j < 8; ++j) lacc[lane][j] = acc[j];
        lsum[lane][0] = sA;  lsum[lane][1] = sB;
    }
    __syncthreads();
    if (wid != 0) return;
    #pragma unroll
    for (int j = 0; j < 8; ++j) acc[j] += lacc[lane][j];
    sA += lsum[lane][0];  sB += lsum[lane][1];

    float invA = 1.f / (sA + 1e-16f);
    float invB = 1.f / (sB + 1e-16f);
    float psrc = 0.f, pdst = 0.f;
    if (act) {
        float o[8];
        #pragma unroll
        for (int j = 0; j < 8; ++j) {
            float v = acc[j] * ((j < sb) ? invA : invB) + b1[col0 + j];
            o[j] = v > 0.f ? v : expm1f(v);
        }
        float4* hp = (float4*)(hout + (size_t)node * 480 + col0);
        hp[0] = make_float4(o[0], o[1], o[2], o[3]);
        hp[1] = make_float4(o[4], o[5], o[6], o[7]);
        #pragma unroll
        for (int j = 0; j < 8; ++j) {
            psrc += o[j] * wa2[col0 + j];
            pdst += o[j] * wa2[480 + col0 + j];
        }
    }
    #pragma unroll
    for (int off = 32; off; off >>= 1) {
        psrc += __shfl_xor(psrc, off);
        pdst += __shfl_xor(pdst, off);
    }
    if (lane == 0) { a2s[node] = psrc; a2d[node] = pdst; }
}

// ---- GAT layer 2, fused: 1 wave per node, U=8; p computed inline (uniform
// across lanes); lane<48 owns cols {2l, 2l+1}.
__global__ __launch_bounds__(256) void gat2_fused(
    const int* __restrict__ row_ptr, const int* __restrict__ csr,
    const float* __restrict__ a_s2, const float* __restrict__ a_d2,
    const __half* __restrict__ xh2h, const float* __restrict__ b2,
    float* __restrict__ out, int N)
{
    int gid = blockIdx.x * blockDim.x + threadIdx.x;
    int node = gid >> 6;
    if (node >= N) return;
    int lane = threadIdx.x & 63;
    bool act = lane < 48;
    float adv = a_d2[node];
    float s = 0.f, ax = 0.f, ay = 0.f;
    int beg = row_ptr[node], end = row_ptr[node + 1];
    constexpr int U = 8;
    for (int e0 = beg; e0 < end; e0 += U) {
        int cnt = end - e0;  if (cnt > U) cnt = U;
        int srcs[U];
        #pragma unroll
        for (int u = 0; u < U; ++u) {
            int t = e0 + u;
            srcs[u] = csr[t < end ? t : (end - 1)];
        }
        float asv[U];
        #pragma unroll
        for (int u = 0; u < U; ++u) asv[u] = a_s2[srcs[u]];
        __half2 gv[U];
        if (act) {
            #pragma unroll
            for (int u = 0; u < U; ++u)
                gv[u] = ((const __half2*)(xh2h + (size_t)srcs[u] * 96))[lane];
        }
        #pragma unroll
        for (int u = 0; u < U; ++u) {
            float ev = asv[u] + adv;
            ev = ev > 0.f ? ev : 0.2f * ev;
            float p = __expf(ev) * ((u < cnt) ? 1.f : 0.f);
            s += p;
            if (act) {
                float2 fg = __half22float2(gv[u]);
                ax += p * fg.x;
                ay += p * fg.y;
            }
        }
    }
    float inv = 1.f / (s + 1e-16f);
    if (act) {
        out[(size_t)node * 96 + 2 * lane]     = ax * inv + b2[2 * lane];
        out[(size_t)node * 96 + 2 * lane + 1] = ay * inv + b2[2 * lane + 1];
    }
}

// xh2h[N,96] = h[N,480] @ W2[480,96], fp16 out (conflict-free row map)
__global__ __launch_bounds__(256) void gemm2_kernel(
    const float* __restrict__ h, const float* __restrict__ W2,
    __half* __restrict__ xh2h, int N)
{
    __shared__ float hs[128][36];
    __shared__ float ws[32][96];
    int t = threadIdx.x;
    int nbase = blockIdx.x * 128;
    int tx = t & 15, ty = t >> 4;
    float acc[8][6];
    #pragma unroll
    for (int i = 0; i < 8; ++i)
        #pragma unroll
        for (int j = 0; j < 6; ++j) acc[i][j] = 0.f;

    for (int k0 = 0; k0 < 480; k0 += 32) {
        #pragma unroll
        for (int i = 0; i < 3; ++i) {
            int f = i * 256 + t;
            int kk = f / 24, c4 = f % 24;
            float4 v = *(const float4*)(W2 + (size_t)(k0 + kk) * 96 + c4 * 4);
            *(float4*)&ws[kk][c4 * 4] = v;
        }
        #pragma unroll
        for (int i = 0; i < 4; ++i) {
            int f = i * 256 + t;
            int node = f >> 3, k4 = f & 7;
            int gn = nbase + node; if (gn > N - 1) gn = N - 1;
            float4 v = *(const float4*)(h + (size_t)gn * 480 + k0 + k4 * 4);
            *(float4*)&hs[node][k4 * 4] = v;
        }
        __syncthreads();
        #pragma unroll
        for (int kk = 0; kk < 32; ++kk) {
            float hv[8], wv[6];
            #pragma unroll
            for (int i = 0; i < 8; ++i) hv[i] = hs[i * 16 + ty][kk];
            #pragma unroll
            for (int j = 0; j < 6; ++j) wv[j] = ws[kk][tx * 6 + j];
            #pragma unroll
            for (int i = 0; i < 8; ++i)
                #pragma unroll
                for (int j = 0; j < 6; ++j)
                    acc[i][j] += hv[i] * wv[j];
        }
        __syncthreads();
    }
    #pragma unroll
    for (int i = 0; i < 8; ++i) {
        int gn = nbase + i * 16 + ty;
        if (gn < N) {
            #pragma unroll
            for (int j = 0; j < 6; ++j)
                xh2h[(size_t)gn * 96 + tx * 6 + j] = __float2half(acc[i][j]);
        }
    }
}

extern "C" void kernel_launch(void* const* d_in, const int* in_sizes, int n_in,
                              void* d_out, int out_size, void* d_ws, size_t ws_size,
                              hipStream_t stream)
{
    const float* x   = (const float*)d_in[0];
    const int*   ei  = (const int*)  d_in[1];
    const float* W1  = (const float*)d_in[2];
    const float* as1 = (const float*)d_in[3];
    const float* ad1 = (const float*)d_in[4];
    const float* b1  = (const float*)d_in[5];
    const float* W2  = (const float*)d_in[6];
    const float* as2 = (const float*)d_in[7];
    const float* ad2 = (const float*)d_in[8];
    const float* b2  = (const float*)d_in[9];
    float* out = (float*)d_out;

    int N  = in_sizes[0] / 4;   // 50000
    int E  = in_sizes[1] / 2;   // 800000
    int EP = E + N;
    int NB = (N + 1023) / 1024; // scan blocks (must be <= 64; 49 here)

    float* f = (float*)d_ws;
    float* hbuf  = f;  f += (size_t)N * 480;
    float* a_s1  = f;  f += (size_t)N * 8;
    float* a_d1  = f;  f += (size_t)N * 8;
    float* a_s2  = f;  f += N;
    float* a_d2  = f;  f += N;
    float* wa1   = f;  f += 64;
    float* wa2   = f;  f += 960;
    __half* xh1h = (__half*)f;
    __half* hp   = xh1h + (size_t)N * 480;
    __half* xh2h = hp;   hp += (size_t)N * 96;
    int* ip      = (int*)hp;
    int* row_ptr = ip;  ip += N + 1;
    int* src_off = ip;  ip += N + 1;
    int* deg_dst = ip;  ip += N;     // deg_dst + deg_src contiguous -> 1 memset
    int* deg_src = ip;  ip += N;
    int* cursor  = ip;  ip += N;
    int* scursor = ip;  ip += N;
    int* part1   = ip;  ip += 64;
    int* part2   = ip;  ip += 64;
    int* esort   = ip;  ip += EP;
    int* csr     = ip;  ip += EP;

    size_t needed = (size_t)((char*)ip - (char*)d_ws);
    if (needed > ws_size) return;  // loud failure if scratch too small

    hipMemsetAsync(deg_dst, 0, (size_t)(2 * N) * sizeof(int), stream);
    prep_kernel<<<1, 512, 0, stream>>>(W1, as1, ad1, W2, as2, ad2, wa1, wa2);
    xh1_kernel<<<(N * 120 + 255) / 256, 256, 0, stream>>>(x, W1, xh1h, N);
    a1_kernel<<<(N + 255) / 256, 256, 0, stream>>>(x, wa1, a_s1, a_d1, N);
    hist_kernel<<<(EP + 255) / 256, 256, 0, stream>>>(ei, E, N, deg_dst, deg_src);
    scan_blk_kernel<<<NB, 1024, 0, stream>>>(deg_dst, N, row_ptr, part1);
    scan_blk_kernel<<<NB, 1024, 0, stream>>>(deg_src, N, src_off, part2);
    scan_part_kernel<<<1, 64, 0, stream>>>(part1, NB, row_ptr, N);
    scan_part_kernel<<<1, 64, 0, stream>>>(part2, NB, src_off, N);
    scan_add_kernel<<<NB, 1024, 0, stream>>>(row_ptr, part1, cursor, N);
    scan_add_kernel<<<NB, 1024, 0, stream>>>(src_off, part2, scursor, N);
    esort_kernel<<<(EP + 255) / 256, 256, 0, stream>>>(ei, E, N, scursor, esort);
    csrfill_kernel<<<(EP + 255) / 256, 256, 0, stream>>>(ei, E, N, esort, cursor, csr);
    gat1_fused<<<N, 128, 0, stream>>>(
        row_ptr, csr, a_s1, a_d1, xh1h, wa2, b1, hbuf, a_s2, a_d2, N);
    gemm2_kernel<<<(N + 127) / 128, 256, 0, stream>>>(hbuf, W2, xh2h, N);
    gat2_fused<<<(N * 64 + 255) / 256, 256, 0, stream>>>(
        row_ptr, csr, a_s2, a_d2, xh2h, b2, out, N);
}